// Round 1
// baseline (314.634 us; speedup 1.0000x reference)
//
#include <hip/hip_runtime.h>
#include <math.h>

#define Wd 8192
#define Bd 32
#define Ttile 64
#define TP 66          // tile + 2 halo
#define NROWP 132      // 128 qk rows + 3 g rows + 1 pad

// workspace layout (float offsets); total ~2.91M floats = 11.7 MB
#define OFF_G    0                         // 3*64
#define OFF_H    192                       // 3
#define OFF_BASE 195                       // 1
#define OFF_XSEQ 256                       // 32*8192
#define OFF_PART (256 + Bd*Wd)             // 32*128*640
#define OFF_S    (OFF_PART + Bd*128*640)   // 32*640
#define OFF_M    (OFF_S + Bd*640)          // 32*3
#define OFF_E    (OFF_M + 96)              // 32*64
#define OFF_F    (OFF_E + Bd*64)           // 32*64

// ---------------- k0: fold sp_w through dwconv(V) & qkv_w into g_j, h_j, base
__global__ void k0_setup(const float* __restrict__ qkv_w, const float* __restrict__ qkv_b,
                         const float* __restrict__ dw_w, const float* __restrict__ dw_b,
                         const float* __restrict__ sp_w, const float* __restrict__ sp_b,
                         float* __restrict__ ws)
{
    int ch = threadIdx.x;   // 0..63
    #pragma unroll
    for (int j = 0; j < 3; j++) {
        float acc = 0.f;
        for (int c = 0; c < 64; c++)
            acc += sp_w[c] * dw_w[(128+c)*9 + 3 + j] * qkv_w[(128+c)*64 + ch];
        ws[OFF_G + j*64 + ch] = acc;
    }
    if (ch == 0) {
        float base = sp_b[0];
        for (int c = 0; c < 64; c++) base += sp_w[c] * dw_b[128+c];
        ws[OFF_BASE] = base;
        #pragma unroll
        for (int j = 0; j < 3; j++) {
            float h = 0.f;
            for (int c = 0; c < 64; c++)
                h += sp_w[c] * dw_w[(128+c)*9 + 3 + j] * qkv_b[128+c];
            ws[OFF_H + j] = h;
        }
    }
}

// ---------------- k1: fused qk projection + dwconv + Gram partials + xseq
__global__ __launch_bounds__(256) void k1_main(const float* __restrict__ x,
    const float* __restrict__ qkv_w, const float* __restrict__ qkv_b,
    const float* __restrict__ dw_w, const float* __restrict__ dw_b,
    float* __restrict__ ws)
{
    __shared__ float xs[64*TP];        // x tile with halo
    __shared__ float pres[NROWP*TP];   // pre-dwconv qk rows + z rows

    const int tid = threadIdx.x;
    const int tile = blockIdx.x, b = blockIdx.y;
    const int w0 = tile * Ttile;
    const float* xb = x + (size_t)b * 64 * Wd;

    // load x tile (zero at global edges)
    for (int i = tid; i < 64*TP; i += 256) {
        int ch = i / TP, p = i - ch*TP;
        int wg = w0 - 1 + p;
        xs[i] = (wg >= 0 && wg < Wd) ? xb[ch*Wd + wg] : 0.f;
    }
    __syncthreads();

    const float* wsg = ws + OFF_G;
    // matmul: (131 rows x 64) @ (64 x 66), 4 rows x 2 cols per thread-tile
    for (int tg = tid; tg < 33*33; tg += 256) {
        int rg = tg / 33, cg = tg - rg*33;
        int p0 = cg * 2;
        int r0 = rg * 4;
        const float* wr[4];
        float bias[4];
        #pragma unroll
        for (int i = 0; i < 4; i++) {
            int r = r0 + i;
            if (r < 128)      { wr[i] = qkv_w + r*64;        bias[i] = qkv_b[r]; }
            else if (r < 131) { wr[i] = wsg + (r-128)*64;    bias[i] = 0.f; }
            else              { wr[i] = qkv_w;               bias[i] = 0.f; } // pad row
        }
        float acc[4][2] = {};
        #pragma unroll 4
        for (int ch = 0; ch < 64; ch += 4) {
            float2 xv0 = *(const float2*)&xs[(ch+0)*TP + p0];
            float2 xv1 = *(const float2*)&xs[(ch+1)*TP + p0];
            float2 xv2 = *(const float2*)&xs[(ch+2)*TP + p0];
            float2 xv3 = *(const float2*)&xs[(ch+3)*TP + p0];
            #pragma unroll
            for (int i = 0; i < 4; i++) {
                float4 wv = *(const float4*)&wr[i][ch];
                acc[i][0] += wv.x*xv0.x; acc[i][1] += wv.x*xv0.y;
                acc[i][0] += wv.y*xv1.x; acc[i][1] += wv.y*xv1.y;
                acc[i][0] += wv.z*xv2.x; acc[i][1] += wv.z*xv2.y;
                acc[i][0] += wv.w*xv3.x; acc[i][1] += wv.w*xv3.y;
            }
        }
        int wg0 = w0 - 1 + p0;
        bool v0 = (wg0   >= 0) && (wg0   < Wd);   // conv zero-pads post-bias qkv
        bool v1 = (wg0+1 >= 0) && (wg0+1 < Wd);
        #pragma unroll
        for (int i = 0; i < 4; i++) {
            pres[(r0+i)*TP + p0    ] = v0 ? (acc[i][0] + bias[i]) : 0.f;
            pres[(r0+i)*TP + p0 + 1] = v1 ? (acc[i][1] + bias[i]) : 0.f;
        }
    }
    __syncthreads();

    // xseq from z rows (128..130): xseq = base + sum_j (z_j[w+j-1] + h_j*valid)
    if (tid < 64) {
        int ww = tid;
        float acc = ws[OFF_BASE];
        #pragma unroll
        for (int j = 0; j < 3; j++) {
            int wg = w0 + ww + j - 1;
            acc += pres[(128+j)*TP + ww + j];
            if (wg >= 0 && wg < Wd) acc += ws[OFF_H + j];
        }
        ws[OFF_XSEQ + b*Wd + w0 + ww] = acc;
    }

    // depthwise 3-tap conv (along w) into registers, then write back in place
    float vals[32];
    #pragma unroll
    for (int it = 0; it < 32; it++) {
        int idx = it*256 + tid;            // 128 rows x 64 positions
        int row = idx >> 6, ww = idx & 63;
        float t0 = dw_w[row*9 + 3], t1 = dw_w[row*9 + 4], t2 = dw_w[row*9 + 5];
        vals[it] = dw_b[row] + t0*pres[row*TP + ww]
                             + t1*pres[row*TP + ww + 1]
                             + t2*pres[row*TP + ww + 2];
    }
    __syncthreads();
    #pragma unroll
    for (int it = 0; it < 32; it++) {
        int idx = it*256 + tid;
        int row = idx >> 6, ww = idx & 63;
        pres[row*TP + ww] = vals[it];
    }
    __syncthreads();

    // Gram partials: per head h, S[c1][c2] = sum_w q*k ; plus sum q^2, sum k^2
    float* part = ws + OFF_PART + (size_t)(b*128 + tile) * 640;
    #pragma unroll
    for (int rep = 0; rep < 2; rep++) {
        int t = rep*256 + tid;                 // 0..511
        int h = t >> 6, c1 = (t >> 3) & 7, c2 = t & 7;
        int rq = h*8 + c1, rk = 64 + h*8 + c2;
        float acc = 0.f;
        #pragma unroll 8
        for (int ww = 0; ww < 64; ww++)
            acc += pres[rq*TP + ww] * pres[rk*TP + ww];
        part[t] = acc;
    }
    if (tid < 128) {
        float acc = 0.f;
        #pragma unroll 8
        for (int ww = 0; ww < 64; ww++) { float q = pres[tid*TP + ww]; acc += q*q; }
        part[512 + tid] = acc;
    }
}

// ---------------- k2: deterministic fixed-order reduction of tile partials
__global__ __launch_bounds__(256) void k2_reduce(const float* __restrict__ part,
                                                 float* __restrict__ S)
{
    int b = blockIdx.x;
    for (int idx = threadIdx.x; idx < 640; idx += 256) {
        float s = 0.f;
        for (int t = 0; t < 128; t++)
            s += part[(size_t)(b*128 + t)*640 + idx];
        S[b*640 + idx] = s;
    }
}

// ---------------- k3: MTL branch scalars m_j[b]
__device__ __forceinline__ float blk_reduce_256(float v, float* sc) {
    #pragma unroll
    for (int off = 32; off > 0; off >>= 1) v += __shfl_down(v, off, 64);
    __syncthreads();
    if ((threadIdx.x & 63) == 0) sc[threadIdx.x >> 6] = v;
    __syncthreads();
    return sc[0] + sc[1] + sc[2] + sc[3];
}

__global__ __launch_bounds__(256) void k3_mtl(const float* __restrict__ xseq,
    const float* __restrict__ up_w, const float* __restrict__ up_b,
    const float* __restrict__ c2_w, const float* __restrict__ c2_b,
    const float* __restrict__ ln2_w, const float* __restrict__ ln2_b,
    const float* __restrict__ c4_w, const float* __restrict__ c4_b,
    const float* __restrict__ ln4_w, const float* __restrict__ ln4_b,
    const float* __restrict__ c6_w, const float* __restrict__ c6_b,
    const float* __restrict__ ln6_w, const float* __restrict__ ln6_b,
    float* __restrict__ wm)
{
    __shared__ float ys[Wd];
    __shared__ float sc[4];
    int br = blockIdx.x, b = blockIdx.y;
    const float *cw, *lw, *lb; float cb; int K, lo;
    if (br == 0)      { cw = c2_w; cb = c2_b[0]; lw = ln2_w; lb = ln2_b; K = 2; lo = 0; }
    else if (br == 1) { cw = c4_w; cb = c4_b[0]; lw = ln4_w; lb = ln4_b; K = 4; lo = 1; }
    else              { cw = c6_w; cb = c6_b[0]; lw = ln6_w; lb = ln6_b; K = 6; lo = 2; }
    float uw = up_w[br], ub = up_b[br];
    const float* xr = xseq + b*Wd;

    float s = 0.f;
    for (int w = threadIdx.x; w < Wd; w += 256) {
        float y = cb;
        for (int m = 0; m < K; m++) {
            int p = w + m - lo;
            if (p >= 0 && p < Wd) y += cw[m] * (uw*xr[p] + ub);  // input zero-padded
        }
        ys[w] = y; s += y;
    }
    float mu = blk_reduce_256(s, sc) * (1.f/Wd);
    float s2 = 0.f;
    for (int w = threadIdx.x; w < Wd; w += 256) { float d = ys[w]-mu; s2 += d*d; }
    float var = blk_reduce_256(s2, sc) * (1.f/Wd);
    float inv = 1.f / sqrtf(var + 1e-5f);
    float se = 0.f;
    for (int w = threadIdx.x; w < Wd; w += 256) {
        float t = (ys[w]-mu)*inv*lw[w] + lb[w];
        se += (t > 0.f) ? t : expm1f(t);
    }
    float m = blk_reduce_256(se, sc) * (1.f/Wd);
    if (threadIdx.x == 0) wm[b*3 + br] = m;
}

// ---------------- k4: norms -> softmax -> alpha/beta -> fold with proj -> E,F
__global__ __launch_bounds__(64) void k4_coeffs(const float* __restrict__ S,
    const float* __restrict__ wm, const float* __restrict__ temperature,
    const float* __restrict__ mp_w, const float* __restrict__ mp_b,
    const float* __restrict__ up_w, const float* __restrict__ up_b,
    const float* __restrict__ proj_w, const float* __restrict__ proj_b,
    float* __restrict__ wsE, float* __restrict__ wsF)
{
    __shared__ float nk[64], alpha[64], beta[64];
    int b = blockIdx.x, t = threadIdx.x;
    const float* Sb = S + b*640;
    float nq_t = fmaxf(sqrtf(Sb[512 + t]), 1e-12f);
    nk[t]      = fmaxf(sqrtf(Sb[576 + t]), 1e-12f);
    __syncthreads();
    int h = t >> 3;
    float temp = temperature[h];
    float lg[8];
    float mx = -1e30f;
    #pragma unroll
    for (int d = 0; d < 8; d++) {
        lg[d] = Sb[8*t + d] / (nq_t * nk[h*8 + d]) * temp;
        mx = fmaxf(mx, lg[d]);
    }
    float sum = 0.f;
    #pragma unroll
    for (int d = 0; d < 8; d++) { lg[d] = expf(lg[d] - mx); sum += lg[d]; }
    float a = 0.f, bb = 0.f;
    #pragma unroll
    for (int d = 0; d < 8; d++) {
        float at = lg[d] / sum;
        a  += at * mp_w[h*8 + d];
        bb += at * mp_b[h*8 + d];
    }
    alpha[t] = a; beta[t] = bb;
    __syncthreads();
    float m2 = wm[b*3+0], m4 = wm[b*3+1], m6 = wm[b*3+2];
    float A = m2*up_w[0] + m4*up_w[1] + m6*up_w[2];
    float C = m2*up_b[0] + m4*up_b[1] + m6*up_b[2];
    float Pa = 0.f, Pb = 0.f;
    for (int c = 0; c < 64; c++) {
        float pw = proj_w[t*64 + c];
        Pa += pw * alpha[c];
        Pb += pw * beta[c];
    }
    wsE[b*64 + t] = A * Pa;
    wsF[b*64 + t] = C * Pa + Pb + proj_b[t];
}

// ---------------- k5: out[b,o,w] = E[b,o]*xseq[b,w] + F[b,o]
__global__ __launch_bounds__(256) void k5_out(const float* __restrict__ ws,
                                              float* __restrict__ out)
{
    int b = blockIdx.z, o = blockIdx.y;
    int idx = blockIdx.x*256 + threadIdx.x;    // 0..2047 (float4 units)
    float e = ws[OFF_E + b*64 + o], f = ws[OFF_F + b*64 + o];
    const float4* xr = (const float4*)(ws + OFF_XSEQ + b*Wd);
    float4 xv = xr[idx];
    float4 r = { e*xv.x + f, e*xv.y + f, e*xv.z + f, e*xv.w + f };
    ((float4*)(out + (size_t)(b*64 + o)*Wd))[idx] = r;
}

extern "C" void kernel_launch(void* const* d_in, const int* in_sizes, int n_in,
                              void* d_out, int out_size, void* d_ws, size_t ws_size,
                              hipStream_t stream) {
    const float* x      = (const float*)d_in[0];
    const float* qkv_w  = (const float*)d_in[1];
    const float* qkv_b  = (const float*)d_in[2];
    const float* dw_w   = (const float*)d_in[3];
    const float* dw_b   = (const float*)d_in[4];
    const float* proj_w = (const float*)d_in[5];
    const float* proj_b = (const float*)d_in[6];
    const float* temperature = (const float*)d_in[7];
    const float* sp_w   = (const float*)d_in[8];
    const float* sp_b   = (const float*)d_in[9];
    const float* up_w   = (const float*)d_in[10];
    const float* up_b   = (const float*)d_in[11];
    const float* c2_w   = (const float*)d_in[12];
    const float* c2_b   = (const float*)d_in[13];
    const float* ln2_w  = (const float*)d_in[14];
    const float* ln2_b  = (const float*)d_in[15];
    const float* c4_w   = (const float*)d_in[16];
    const float* c4_b   = (const float*)d_in[17];
    const float* ln4_w  = (const float*)d_in[18];
    const float* ln4_b  = (const float*)d_in[19];
    const float* c6_w   = (const float*)d_in[20];
    const float* c6_b   = (const float*)d_in[21];
    const float* ln6_w  = (const float*)d_in[22];
    const float* ln6_b  = (const float*)d_in[23];
    const float* mp_w   = (const float*)d_in[24];
    const float* mp_b   = (const float*)d_in[25];
    float* ws  = (float*)d_ws;
    float* out = (float*)d_out;

    k0_setup<<<1, 64, 0, stream>>>(qkv_w, qkv_b, dw_w, dw_b, sp_w, sp_b, ws);
    k1_main<<<dim3(128, 32), 256, 0, stream>>>(x, qkv_w, qkv_b, dw_w, dw_b, ws);
    k2_reduce<<<32, 256, 0, stream>>>(ws + OFF_PART, ws + OFF_S);
    k3_mtl<<<dim3(3, 32), 256, 0, stream>>>(ws + OFF_XSEQ, up_w, up_b,
        c2_w, c2_b, ln2_w, ln2_b, c4_w, c4_b, ln4_w, ln4_b, c6_w, c6_b, ln6_w, ln6_b,
        ws + OFF_M);
    k4_coeffs<<<32, 64, 0, stream>>>(ws + OFF_S, ws + OFF_M, temperature, mp_w, mp_b,
        up_w, up_b, proj_w, proj_b, ws + OFF_E, ws + OFF_F);
    k5_out<<<dim3(8, 64, 32), 256, 0, stream>>>(ws, out);
}

// Round 2
// 213.711 us; speedup vs baseline: 1.4722x; 1.4722x over previous
//
#include <hip/hip_runtime.h>
#include <math.h>

#define Wd 8192
#define Bd 32
#define Ttile 64
#define NSLOT 80        // 5 MFMA N-tiles of 16; slots 0..65 valid (w0-1 .. w0+64)
#define PRES_LD 68      // pres stride (floats), 16B-aligned rows
#define XS_LD 81        // fp32 staging stride

// LDS byte layout (union):
//   [0, 20736)          xs_f32  64 x 81 f32          (phase 1-2)
//   [20736, 30976)      xt_hi   80 x 64 bf16 swizzled (phase 2-3)
//   [30976, 41216)      xt_lo   80 x 64 bf16 swizzled (phase 2-3)
//   [0, 35632)          pres    131 x 68 f32          (phase 4+, overlays xs/xt)
#define SM_BYTES 41216
#define XT_HI_OFF 20736
#define XT_LO_OFF 30976

// workspace layout (float offsets)
#define OFF_G    0                         // 3*64
#define OFF_H    192                       // 3
#define OFF_BASE 195                       // 1
#define OFF_XSEQ 256                       // 32*8192
#define OFF_PART (256 + Bd*Wd)             // 32*128*640
#define OFF_S    (OFF_PART + Bd*128*640)   // 32*640
#define OFF_M    (OFF_S + Bd*640)          // 32*3
#define OFF_E    (OFF_M + 96)              // 32*64
#define OFF_F    (OFF_E + Bd*64)           // 32*64
#define OFF_FRAG (OFF_F + Bd*64)           // 2 ver * 9 mt * 2 kb * 64 lane * 4 (uint4) = 9216 f

typedef __attribute__((ext_vector_type(8))) short bf16x8;
typedef __attribute__((ext_vector_type(4))) float f32x4;

__device__ __forceinline__ unsigned short bf16_rne(float v) {
    unsigned u = __builtin_bit_cast(unsigned, v);
    return (unsigned short)((u + 0x7FFFu + ((u >> 16) & 1u)) >> 16);
}
__device__ __forceinline__ float bf16_to_f(unsigned short h) {
    return __builtin_bit_cast(float, (unsigned)h << 16);
}

// ---------------- k0: fold sp_w through dwconv(V)+qkv into g/h/base, then pack
// bf16 hi/lo A-fragments of the 131x64 weight matrix in MFMA 16x16x32 order.
__global__ __launch_bounds__(256) void k0_setup(const float* __restrict__ qkv_w,
                         const float* __restrict__ qkv_b,
                         const float* __restrict__ dw_w, const float* __restrict__ dw_b,
                         const float* __restrict__ sp_w, const float* __restrict__ sp_b,
                         float* __restrict__ ws)
{
    int tid = threadIdx.x;
    if (tid < 64) {
        int ch = tid;
        #pragma unroll
        for (int j = 0; j < 3; j++) {
            float acc = 0.f;
            for (int c = 0; c < 64; c++)
                acc += sp_w[c] * dw_w[(128+c)*9 + 3 + j] * qkv_w[(128+c)*64 + ch];
            ws[OFF_G + j*64 + ch] = acc;
        }
        if (ch == 0) {
            float base = sp_b[0];
            for (int c = 0; c < 64; c++) base += sp_w[c] * dw_b[128+c];
            ws[OFF_BASE] = base;
            #pragma unroll
            for (int j = 0; j < 3; j++) {
                float h = 0.f;
                for (int c = 0; c < 64; c++)
                    h += sp_w[c] * dw_w[(128+c)*9 + 3 + j] * qkv_b[128+c];
                ws[OFF_H + j] = h;
            }
        }
    }
    __syncthreads();
    // pack fragments: item = (ver, mt, kb, lane)
    for (int it = tid; it < 36*64; it += 256) {
        int lane = it & 63;
        int cidx = it >> 6;          // 0..35
        int ver = cidx / 18;
        int rem = cidx - ver*18;
        int mt = rem >> 1, kb = rem & 1;
        int row = mt*16 + (lane & 15);
        int ks  = kb*32 + (lane >> 4)*8;
        unsigned short u[8];
        #pragma unroll
        for (int e = 0; e < 8; e++) {
            int k = ks + e;
            float v = 0.f;
            if (row < 128)      v = qkv_w[row*64 + k];
            else if (row < 131) v = ws[OFF_G + (row-128)*64 + k];
            unsigned short h = bf16_rne(v);
            if (ver == 0) u[e] = h;
            else          u[e] = bf16_rne(v - bf16_to_f(h));
        }
        unsigned* dst = (unsigned*)(ws + OFF_FRAG) + (ver*1152 + (mt*2+kb)*64 + lane)*4;
        dst[0] = (unsigned)u[0] | ((unsigned)u[1] << 16);
        dst[1] = (unsigned)u[2] | ((unsigned)u[3] << 16);
        dst[2] = (unsigned)u[4] | ((unsigned)u[5] << 16);
        dst[3] = (unsigned)u[6] | ((unsigned)u[7] << 16);
    }
}

// ---------------- k1: MFMA qk/z projection + dwconv + Gram partials + xseq
__global__ __launch_bounds__(256, 3) void k1_main(const float* __restrict__ x,
    const float* __restrict__ qkv_b,
    const float* __restrict__ dw_w, const float* __restrict__ dw_b,
    float* __restrict__ ws)
{
    __shared__ __align__(16) unsigned char smem[SM_BYTES];
    __shared__ float sbias[132];

    const int tid = threadIdx.x;
    const int lane = tid & 63, wv = tid >> 6;
    const int tile = blockIdx.x, b = blockIdx.y;
    const int w0 = tile * Ttile;
    const float* xb = x + (size_t)b * 64 * Wd;

    float* xs = (float*)smem;          // 64 x 81
    float* pres = (float*)smem;        // 131 x 68 (after GEMM)

    // ---- phase 1: global -> xs_f32 (aligned float4 loads, 21 chunks/row)
    for (int i = tid; i < 64*21; i += 256) {
        int ch = i / 21, j = i - ch*21;
        int wg = w0 - 4 + 4*j;
        float vv[4];
        if (wg >= 0 && wg + 3 < Wd) {
            float4 t = *(const float4*)(xb + (size_t)ch*Wd + wg);
            vv[0]=t.x; vv[1]=t.y; vv[2]=t.z; vv[3]=t.w;
        } else {
            #pragma unroll
            for (int e = 0; e < 4; e++) {
                int g = wg + e;
                vv[e] = (g >= 0 && g < Wd) ? xb[(size_t)ch*Wd + g] : 0.f;
            }
        }
        #pragma unroll
        for (int e = 0; e < 4; e++) {
            int p = wg + e - (w0 - 1);
            if ((unsigned)p < (unsigned)NSLOT) xs[ch*XS_LD + p] = vv[e];
        }
    }
    if (tid < 132) sbias[tid] = (tid < 128) ? qkv_b[tid] : 0.f;
    __syncthreads();

    // ---- phase 2: transpose + bf16 hi/lo split into swizzled xt
    for (int i = tid; i < NSLOT*8; i += 256) {
        int w = i >> 3, c = i & 7;
        unsigned hi2[4], lo2[4];
        #pragma unroll
        for (int e2 = 0; e2 < 4; e2++) {
            unsigned short h0, h1, l0, l1;
            {
                float v = xs[(c*8 + 2*e2    )*XS_LD + w];
                h0 = bf16_rne(v); l0 = bf16_rne(v - bf16_to_f(h0));
            }
            {
                float v = xs[(c*8 + 2*e2 + 1)*XS_LD + w];
                h1 = bf16_rne(v); l1 = bf16_rne(v - bf16_to_f(h1));
            }
            hi2[e2] = (unsigned)h0 | ((unsigned)h1 << 16);
            lo2[e2] = (unsigned)l0 | ((unsigned)l1 << 16);
        }
        int boff = w*128 + ((c ^ (w & 7)) << 4);
        unsigned* dh = (unsigned*)(smem + XT_HI_OFF + boff);
        unsigned* dl = (unsigned*)(smem + XT_LO_OFF + boff);
        dh[0]=hi2[0]; dh[1]=hi2[1]; dh[2]=hi2[2]; dh[3]=hi2[3];
        dl[0]=lo2[0]; dl[1]=lo2[1]; dl[2]=lo2[2]; dl[3]=lo2[3];
    }
    __syncthreads();

    // ---- phase 3: GEMM  C(131x80) = W(131x64) @ X(64x80), hi/lo 3-pass
    f32x4 acc[3][5];
    #pragma unroll
    for (int i = 0; i < 3; i++)
        #pragma unroll
        for (int nt = 0; nt < 5; nt++)
            acc[i][nt] = (f32x4){0.f,0.f,0.f,0.f};

    const uint4* fragbase = (const uint4*)(ws + OFF_FRAG);
    #pragma unroll
    for (int kb = 0; kb < 2; kb++) {
        bf16x8 bh[5], bl[5];
        #pragma unroll
        for (int nt = 0; nt < 5; nt++) {
            int wslot = nt*16 + (lane & 15);
            int chunk = (kb*4 + (lane >> 4)) ^ (wslot & 7);
            int boff = wslot*128 + (chunk << 4);
            bh[nt] = *(const bf16x8*)(smem + XT_HI_OFF + boff);
            bl[nt] = *(const bf16x8*)(smem + XT_LO_OFF + boff);
        }
        bf16x8 ah[3], al[3];
        #pragma unroll
        for (int i = 0; i < 3; i++) {
            int mt = wv + 4*i;
            if (mt < 9) {
                ah[i] = __builtin_bit_cast(bf16x8, fragbase[       (mt*2+kb)*64 + lane]);
                al[i] = __builtin_bit_cast(bf16x8, fragbase[1152 + (mt*2+kb)*64 + lane]);
            }
        }
        #pragma unroll
        for (int i = 0; i < 3; i++) {
            int mt = wv + 4*i;
            if (mt < 9) {
                #pragma unroll
                for (int nt = 0; nt < 5; nt++) {
                    acc[i][nt] = __builtin_amdgcn_mfma_f32_16x16x32_bf16(ah[i], bh[nt], acc[i][nt], 0, 0, 0);
                    acc[i][nt] = __builtin_amdgcn_mfma_f32_16x16x32_bf16(al[i], bh[nt], acc[i][nt], 0, 0, 0);
                    acc[i][nt] = __builtin_amdgcn_mfma_f32_16x16x32_bf16(ah[i], bl[nt], acc[i][nt], 0, 0, 0);
                }
            }
        }
    }
    __syncthreads();   // xt dead; pres overlays

    // ---- phase 4: write pres (+bias, zero at global edges)
    #pragma unroll
    for (int i = 0; i < 3; i++) {
        int mt = wv + 4*i;
        if (mt < 9) {
            #pragma unroll
            for (int nt = 0; nt < 5; nt++) {
                int slot = nt*16 + (lane & 15);
                #pragma unroll
                for (int r = 0; r < 4; r++) {
                    int row = mt*16 + (lane >> 4)*4 + r;
                    if (row < 131 && slot < 66) {
                        int wg = w0 - 1 + slot;
                        float v = (wg >= 0 && wg < Wd) ? acc[i][nt][r] + sbias[row] : 0.f;
                        pres[row*PRES_LD + slot] = v;
                    }
                }
            }
        }
    }
    __syncthreads();

    // ---- phase 5a: xseq from z rows (128..130)
    if (tid < 64) {
        int ww = tid;
        float acc2 = ws[OFF_BASE];
        #pragma unroll
        for (int j = 0; j < 3; j++) {
            int wg = w0 + ww + j - 1;
            acc2 += pres[(128+j)*PRES_LD + ww + j];
            if (wg >= 0 && wg < Wd) acc2 += ws[OFF_H + j];
        }
        ws[OFF_XSEQ + b*Wd + w0 + ww] = acc2;
    }

    // ---- phase 5b: depthwise 3-tap conv into regs, write back in place
    float vals[32];
    #pragma unroll
    for (int it = 0; it < 32; it++) {
        int idx = it*256 + tid;            // 128 rows x 64 positions
        int row = idx >> 6, ww = idx & 63;
        float t0 = dw_w[row*9 + 3], t1 = dw_w[row*9 + 4], t2 = dw_w[row*9 + 5];
        vals[it] = dw_b[row] + t0*pres[row*PRES_LD + ww]
                             + t1*pres[row*PRES_LD + ww + 1]
                             + t2*pres[row*PRES_LD + ww + 2];
    }
    __syncthreads();
    #pragma unroll
    for (int it = 0; it < 32; it++) {
        int idx = it*256 + tid;
        int row = idx >> 6, ww = idx & 63;
        pres[row*PRES_LD + ww] = vals[it];
    }
    __syncthreads();

    // ---- phase 6: Gram partials (vectorized) + norms
    float* part = ws + OFF_PART + (size_t)(b*128 + tile) * 640;
    #pragma unroll
    for (int rep = 0; rep < 2; rep++) {
        int t = rep*256 + tid;                 // 0..511
        int h = t >> 6, c1 = (t >> 3) & 7, c2 = t & 7;
        const float4* qp = (const float4*)(pres + (h*8 + c1)*PRES_LD);
        const float4* kp = (const float4*)(pres + (64 + h*8 + c2)*PRES_LD);
        float acc3 = 0.f;
        #pragma unroll
        for (int i = 0; i < 16; i++) {
            float4 qv = qp[i], kv = kp[i];
            acc3 += qv.x*kv.x + qv.y*kv.y + qv.z*kv.z + qv.w*kv.w;
        }
        part[t] = acc3;
    }
    if (tid < 128) {
        const float4* qp = (const float4*)(pres + tid*PRES_LD);
        float acc3 = 0.f;
        #pragma unroll
        for (int i = 0; i < 16; i++) {
            float4 qv = qp[i];
            acc3 += qv.x*qv.x + qv.y*qv.y + qv.z*qv.z + qv.w*qv.w;
        }
        part[512 + tid] = acc3;
    }
}

// ---------------- k2: deterministic fixed-order reduction of tile partials
__global__ __launch_bounds__(256) void k2_reduce(const float* __restrict__ part,
                                                 float* __restrict__ S)
{
    int b = blockIdx.x;
    for (int idx = threadIdx.x; idx < 640; idx += 256) {
        float s = 0.f;
        for (int t = 0; t < 128; t++)
            s += part[(size_t)(b*128 + t)*640 + idx];
        S[b*640 + idx] = s;
    }
}

// ---------------- k3: MTL branch scalars m_j[b]
__device__ __forceinline__ float blk_reduce_256(float v, float* sc) {
    #pragma unroll
    for (int off = 32; off > 0; off >>= 1) v += __shfl_down(v, off, 64);
    __syncthreads();
    if ((threadIdx.x & 63) == 0) sc[threadIdx.x >> 6] = v;
    __syncthreads();
    return sc[0] + sc[1] + sc[2] + sc[3];
}

__global__ __launch_bounds__(256) void k3_mtl(const float* __restrict__ xseq,
    const float* __restrict__ up_w, const float* __restrict__ up_b,
    const float* __restrict__ c2_w, const float* __restrict__ c2_b,
    const float* __restrict__ ln2_w, const float* __restrict__ ln2_b,
    const float* __restrict__ c4_w, const float* __restrict__ c4_b,
    const float* __restrict__ ln4_w, const float* __restrict__ ln4_b,
    const float* __restrict__ c6_w, const float* __restrict__ c6_b,
    const float* __restrict__ ln6_w, const float* __restrict__ ln6_b,
    float* __restrict__ wm)
{
    __shared__ float ys[Wd];
    __shared__ float sc[4];
    int br = blockIdx.x, b = blockIdx.y;
    const float *cw, *lw, *lb; float cb; int K, lo;
    if (br == 0)      { cw = c2_w; cb = c2_b[0]; lw = ln2_w; lb = ln2_b; K = 2; lo = 0; }
    else if (br == 1) { cw = c4_w; cb = c4_b[0]; lw = ln4_w; lb = ln4_b; K = 4; lo = 1; }
    else              { cw = c6_w; cb = c6_b[0]; lw = ln6_w; lb = ln6_b; K = 6; lo = 2; }
    float uw = up_w[br], ub = up_b[br];
    const float* xr = xseq + b*Wd;

    float s = 0.f;
    for (int w = threadIdx.x; w < Wd; w += 256) {
        float y = cb;
        for (int m = 0; m < K; m++) {
            int p = w + m - lo;
            if (p >= 0 && p < Wd) y += cw[m] * (uw*xr[p] + ub);
        }
        ys[w] = y; s += y;
    }
    float mu = blk_reduce_256(s, sc) * (1.f/Wd);
    float s2 = 0.f;
    for (int w = threadIdx.x; w < Wd; w += 256) { float d = ys[w]-mu; s2 += d*d; }
    float var = blk_reduce_256(s2, sc) * (1.f/Wd);
    float inv = 1.f / sqrtf(var + 1e-5f);
    float se = 0.f;
    for (int w = threadIdx.x; w < Wd; w += 256) {
        float t = (ys[w]-mu)*inv*lw[w] + lb[w];
        se += (t > 0.f) ? t : expm1f(t);
    }
    float m = blk_reduce_256(se, sc) * (1.f/Wd);
    if (threadIdx.x == 0) wm[b*3 + br] = m;
}

// ---------------- k4: norms -> softmax -> alpha/beta -> fold with proj -> E,F
__global__ __launch_bounds__(64) void k4_coeffs(const float* __restrict__ S,
    const float* __restrict__ wm, const float* __restrict__ temperature,
    const float* __restrict__ mp_w, const float* __restrict__ mp_b,
    const float* __restrict__ up_w, const float* __restrict__ up_b,
    const float* __restrict__ proj_w, const float* __restrict__ proj_b,
    float* __restrict__ wsE, float* __restrict__ wsF)
{
    __shared__ float nk[64], alpha[64], beta[64];
    int b = blockIdx.x, t = threadIdx.x;
    const float* Sb = S + b*640;
    float nq_t = fmaxf(sqrtf(Sb[512 + t]), 1e-12f);
    nk[t]      = fmaxf(sqrtf(Sb[576 + t]), 1e-12f);
    __syncthreads();
    int h = t >> 3;
    float temp = temperature[h];
    float lg[8];
    float mx = -1e30f;
    #pragma unroll
    for (int d = 0; d < 8; d++) {
        lg[d] = Sb[8*t + d] / (nq_t * nk[h*8 + d]) * temp;
        mx = fmaxf(mx, lg[d]);
    }
    float sum = 0.f;
    #pragma unroll
    for (int d = 0; d < 8; d++) { lg[d] = expf(lg[d] - mx); sum += lg[d]; }
    float a = 0.f, bb = 0.f;
    #pragma unroll
    for (int d = 0; d < 8; d++) {
        float at = lg[d] / sum;
        a  += at * mp_w[h*8 + d];
        bb += at * mp_b[h*8 + d];
    }
    alpha[t] = a; beta[t] = bb;
    __syncthreads();
    float m2 = wm[b*3+0], m4 = wm[b*3+1], m6 = wm[b*3+2];
    float A = m2*up_w[0] + m4*up_w[1] + m6*up_w[2];
    float C = m2*up_b[0] + m4*up_b[1] + m6*up_b[2];
    float Pa = 0.f, Pb = 0.f;
    for (int c = 0; c < 64; c++) {
        float pw = proj_w[t*64 + c];
        Pa += pw * alpha[c];
        Pb += pw * beta[c];
    }
    wsE[b*64 + t] = A * Pa;
    wsF[b*64 + t] = C * Pa + Pb + proj_b[t];
}

// ---------------- k5: out[b,o,w] = E[b,o]*xseq[b,w] + F[b,o]
__global__ __launch_bounds__(256) void k5_out(const float* __restrict__ ws,
                                              float* __restrict__ out)
{
    int b = blockIdx.z, o = blockIdx.y;
    int idx = blockIdx.x*256 + threadIdx.x;    // 0..2047 (float4 units)
    float e = ws[OFF_E + b*64 + o], f = ws[OFF_F + b*64 + o];
    const float4* xr = (const float4*)(ws + OFF_XSEQ + b*Wd);
    float4 xv = xr[idx];
    float4 r = { e*xv.x + f, e*xv.y + f, e*xv.z + f, e*xv.w + f };
    ((float4*)(out + (size_t)(b*64 + o)*Wd))[idx] = r;
}

extern "C" void kernel_launch(void* const* d_in, const int* in_sizes, int n_in,
                              void* d_out, int out_size, void* d_ws, size_t ws_size,
                              hipStream_t stream) {
    const float* x      = (const float*)d_in[0];
    const float* qkv_w  = (const float*)d_in[1];
    const float* qkv_b  = (const float*)d_in[2];
    const float* dw_w   = (const float*)d_in[3];
    const float* dw_b   = (const float*)d_in[4];
    const float* proj_w = (const float*)d_in[5];
    const float* proj_b = (const float*)d_in[6];
    const float* temperature = (const float*)d_in[7];
    const float* sp_w   = (const float*)d_in[8];
    const float* sp_b   = (const float*)d_in[9];
    const float* up_w   = (const float*)d_in[10];
    const float* up_b   = (const float*)d_in[11];
    const float* c2_w   = (const float*)d_in[12];
    const float* c2_b   = (const float*)d_in[13];
    const float* ln2_w  = (const float*)d_in[14];
    const float* ln2_b  = (const float*)d_in[15];
    const float* c4_w   = (const float*)d_in[16];
    const float* c4_b   = (const float*)d_in[17];
    const float* ln4_w  = (const float*)d_in[18];
    const float* ln4_b  = (const float*)d_in[19];
    const float* c6_w   = (const float*)d_in[20];
    const float* c6_b   = (const float*)d_in[21];
    const float* ln6_w  = (const float*)d_in[22];
    const float* ln6_b  = (const float*)d_in[23];
    const float* mp_w   = (const float*)d_in[24];
    const float* mp_b   = (const float*)d_in[25];
    float* ws  = (float*)d_ws;
    float* out = (float*)d_out;

    k0_setup<<<1, 256, 0, stream>>>(qkv_w, qkv_b, dw_w, dw_b, sp_w, sp_b, ws);
    k1_main<<<dim3(128, 32), 256, 0, stream>>>(x, qkv_b, dw_w, dw_b, ws);
    k2_reduce<<<32, 256, 0, stream>>>(ws + OFF_PART, ws + OFF_S);
    k3_mtl<<<dim3(3, 32), 256, 0, stream>>>(ws + OFF_XSEQ, up_w, up_b,
        c2_w, c2_b, ln2_w, ln2_b, c4_w, c4_b, ln4_w, ln4_b, c6_w, c6_b, ln6_w, ln6_b,
        ws + OFF_M);
    k4_coeffs<<<32, 64, 0, stream>>>(ws + OFF_S, ws + OFF_M, temperature, mp_w, mp_b,
        up_w, up_b, proj_w, proj_b, ws + OFF_E, ws + OFF_F);
    k5_out<<<dim3(8, 64, 32), 256, 0, stream>>>(ws, out);
}

// Round 3
// 144.681 us; speedup vs baseline: 2.1747x; 1.4771x over previous
//
#include <hip/hip_runtime.h>
#include <hip/hip_bf16.h>
#include <math.h>

#define Wd 8192
#define Bd 32
#define Ttile 64

// ws layout (float offsets)
#define OFF_G    0                          // 3*64
#define OFF_H    192                        // 3
#define OFF_BASE 195                        // 1
#define OFF_XSEQ 256                        // 32*8192
#define OFF_PART (256 + Bd*Wd)              // [b][640][128]
#define OFF_S    (OFF_PART + Bd*640*128)    // 32*640
#define OFF_M    (OFF_S + Bd*640)           // 32*3
#define OFF_E    (OFF_M + 96)               // (unused, kept for layout)
#define OFF_F    (OFF_E + Bd*64)
#define OFF_FRAG (OFF_F + Bd*64)            // 2 ver * 9 nt * 2 kb * 64 lane * uint4

typedef __attribute__((ext_vector_type(8))) short bf16x8;
typedef __attribute__((ext_vector_type(4))) float f32x4;

__device__ __forceinline__ unsigned short f2bf(float v) {
    return __builtin_bit_cast(unsigned short, __float2bfloat16(v));
}
__device__ __forceinline__ float bf2f(unsigned short h) {
    return __builtin_bit_cast(float, (unsigned)h << 16);
}
__device__ __forceinline__ void split2(float v0, float v1, unsigned& hw, unsigned& lw) {
    unsigned short h0 = f2bf(v0), h1 = f2bf(v1);
    unsigned short l0 = f2bf(v0 - bf2f(h0)), l1 = f2bf(v1 - bf2f(h1));
    hw = (unsigned)h0 | ((unsigned)h1 << 16);
    lw = (unsigned)l0 | ((unsigned)l1 << 16);
}

// ---------------- k0: fold sp_w through dwconv(V)+qkv into g/h/base; pack
// hi/lo bf16 B-fragments (col = weight-row, k = channel) of the 131x64 matrix.
__global__ __launch_bounds__(256) void k0_setup(const float* __restrict__ qkv_w,
                         const float* __restrict__ qkv_b,
                         const float* __restrict__ dw_w, const float* __restrict__ dw_b,
                         const float* __restrict__ sp_w, const float* __restrict__ sp_b,
                         float* __restrict__ ws)
{
    int tid = threadIdx.x;
    if (tid < 192) {
        int j = tid >> 6, ch = tid & 63;
        float acc = 0.f;
        for (int c = 0; c < 64; c++)
            acc += sp_w[c] * dw_w[(128+c)*9 + 3 + j] * qkv_w[(128+c)*64 + ch];
        ws[OFF_G + j*64 + ch] = acc;
    } else if (tid < 195) {
        int j = tid - 192;
        float h = 0.f;
        for (int c = 0; c < 64; c++)
            h += sp_w[c] * dw_w[(128+c)*9 + 3 + j] * qkv_b[128+c];
        ws[OFF_H + j] = h;
    } else if (tid == 195) {
        float base = sp_b[0];
        for (int c = 0; c < 64; c++) base += sp_w[c] * dw_b[128+c];
        ws[OFF_BASE] = base;
    }
    __syncthreads();
    // pack fragments: item = (ver, nt, kb, lane); row = nt*16+(l&15), k = kb*32+(l>>4)*8+e
    for (int it = tid; it < 36*64; it += 256) {
        int lane = it & 63;
        int cidx = it >> 6;          // 0..35
        int ver = cidx / 18;
        int rem = cidx - ver*18;
        int nt = rem >> 1, kb = rem & 1;
        int row = nt*16 + (lane & 15);
        int ks  = kb*32 + (lane >> 4)*8;
        unsigned short u[8];
        #pragma unroll
        for (int e = 0; e < 8; e++) {
            int k = ks + e;
            float v = 0.f;
            if (row < 128)      v = qkv_w[row*64 + k];
            else if (row < 131) v = ws[OFF_G + (row-128)*64 + k];
            unsigned short h = f2bf(v);
            if (ver == 0) u[e] = h;
            else          u[e] = f2bf(v - bf2f(h));
        }
        unsigned* dst = (unsigned*)(ws + OFF_FRAG) + (ver*1152 + (nt*2+kb)*64 + lane)*4;
        dst[0] = (unsigned)u[0] | ((unsigned)u[1] << 16);
        dst[1] = (unsigned)u[2] | ((unsigned)u[3] << 16);
        dst[2] = (unsigned)u[4] | ((unsigned)u[5] << 16);
        dst[3] = (unsigned)u[6] | ((unsigned)u[7] << 16);
    }
}

// ---------------- k1: barrier-free fused MFMA projection + reg-conv + MFMA Gram
// LDS: qkhi [128 rows][144 B], qklo same, zlds 3x84 f32
#define QKHI 0
#define QKLO 18432
#define ZLDS 36864
#define SMEM_BYTES (36864 + 1024)

__global__ __launch_bounds__(256, 3) void k1_main(const float* __restrict__ x,
    const float* __restrict__ qkv_b, const float* __restrict__ dw_w,
    const float* __restrict__ dw_b, float* __restrict__ ws)
{
    __shared__ __align__(16) unsigned char smem[SMEM_BYTES];
    const int tid = threadIdx.x, lane = tid & 63, wv = tid >> 6;
    const int g = lane >> 4, lr = lane & 15;
    const int tile = blockIdx.x, b = blockIdx.y;
    const int w0 = tile * Ttile;
    const float* xb = x + (size_t)b * 64 * Wd;
    const bool safe = (tile != 0) && (tile != 127);

    // ---- GEMM: C'(80 slots x 131 rows) = X^T(80x64) @ W^T(64x131)
    f32x4 acc[3][5];
    #pragma unroll
    for (int i = 0; i < 3; i++)
        #pragma unroll
        for (int m = 0; m < 5; m++) acc[i][m] = (f32x4){0.f,0.f,0.f,0.f};
    const uint4* fragbase = (const uint4*)(ws + OFF_FRAG);

    #pragma unroll
    for (int kb = 0; kb < 2; kb++) {
        bf16x8 axh[5], axl[5];
        #pragma unroll
        for (int mt = 0; mt < 5; mt++) {
            int pos = w0 - 1 + mt*16 + lr;
            int posc = min(max(pos, 0), Wd - 1);
            const float* p = xb + (size_t)(kb*32 + g*8) * Wd + posc;
            float v[8];
            if (safe) {
                #pragma unroll
                for (int e = 0; e < 8; e++) v[e] = p[(size_t)e * Wd];
            } else {
                bool vld = (pos >= 0) && (pos < Wd);
                #pragma unroll
                for (int e = 0; e < 8; e++) { float t = p[(size_t)e * Wd]; v[e] = vld ? t : 0.f; }
            }
            uint4 uh, ul;
            split2(v[0], v[1], uh.x, ul.x);
            split2(v[2], v[3], uh.y, ul.y);
            split2(v[4], v[5], uh.z, ul.z);
            split2(v[6], v[7], uh.w, ul.w);
            axh[mt] = __builtin_bit_cast(bf16x8, uh);
            axl[mt] = __builtin_bit_cast(bf16x8, ul);
        }
        #pragma unroll
        for (int nti = 0; nti < 3; nti++) {
            if (nti < 2 || wv == 0) {
                int nt = (nti == 2) ? 8 : (wv + nti*4);
                bf16x8 bh = __builtin_bit_cast(bf16x8, fragbase[(nt*2+kb)*64 + lane]);
                bf16x8 bl = __builtin_bit_cast(bf16x8, fragbase[1152 + (nt*2+kb)*64 + lane]);
                #pragma unroll
                for (int mt = 0; mt < 5; mt++) {
                    acc[nti][mt] = __builtin_amdgcn_mfma_f32_16x16x32_bf16(axh[mt], bh, acc[nti][mt], 0,0,0);
                    acc[nti][mt] = __builtin_amdgcn_mfma_f32_16x16x32_bf16(axl[mt], bh, acc[nti][mt], 0,0,0);
                    acc[nti][mt] = __builtin_amdgcn_mfma_f32_16x16x32_bf16(axh[mt], bl, acc[nti][mt], 0,0,0);
                }
            }
        }
    }

    // ---- epilogue: D[col=lr (row of W)][row=(g*4+r) (w-slot)]
    unsigned short* qkhi = (unsigned short*)(smem + QKHI);
    unsigned short* qklo = (unsigned short*)(smem + QKLO);
    float* zlds = (float*)(smem + ZLDS);

    #pragma unroll
    for (int nti = 0; nti < 3; nti++) {
        if (!(nti < 2 || wv == 0)) continue;
        int nt = (nti == 2) ? 8 : (wv + nti*4);
        int row = nt*16 + lr;
        if (nt == 8) {
            // z rows 128..130: no bias, OOB already zero (A zeroed); store f32
            if (lr < 3) {
                #pragma unroll
                for (int mt = 0; mt < 5; mt++) {
                    float4 vz = { acc[2][mt][0], acc[2][mt][1], acc[2][mt][2], acc[2][mt][3] };
                    *(float4*)(zlds + lr*84 + mt*16 + g*4) = vz;
                }
            }
        } else {
            float bias = qkv_b[row];
            float tb = dw_b[row];
            float t0 = dw_w[row*9+3], t1 = dw_w[row*9+4], t2 = dw_w[row*9+5];
            float4 v[5];
            #pragma unroll
            for (int mt = 0; mt < 5; mt++) {
                #pragma unroll
                for (int r = 0; r < 4; r++) {
                    float val = acc[nti][mt][r] + bias;
                    if (!safe) {
                        int pos = w0 - 1 + mt*16 + g*4 + r;
                        if (pos < 0 || pos >= Wd) val = 0.f;
                    }
                    ((float*)&v[mt])[r] = val;
                }
            }
            int src = (lane + 16) & 63;    // same (lane&15), next slot-group
            #pragma unroll
            for (int mt = 0; mt < 4; mt++) {
                float a0 = __shfl(v[mt].x,   src), b0 = __shfl(v[mt+1].x, src);
                float a1 = __shfl(v[mt].y,   src), b1 = __shfl(v[mt+1].y, src);
                float in4 = (lane < 48) ? a0 : b0;
                float in5 = (lane < 48) ? a1 : b1;
                float o0 = tb + t0*v[mt].x + t1*v[mt].y + t2*v[mt].z;
                float o1 = tb + t0*v[mt].y + t1*v[mt].z + t2*v[mt].w;
                float o2 = tb + t0*v[mt].z + t1*v[mt].w + t2*in4;
                float o3 = tb + t0*v[mt].w + t1*in4     + t2*in5;
                uint2 hw, lw;
                split2(o0, o1, hw.x, lw.x);
                split2(o2, o3, hw.y, lw.y);
                int boff = row*144 + (mt*16 + g*4)*2;
                *(uint2*)((unsigned char*)qkhi + boff) = hw;
                *(uint2*)((unsigned char*)qklo + boff) = lw;
            }
        }
    }

    // ---- xseq (wave 0 only; reads zlds written by wave 0 — no barrier needed)
    if (tid < 64) {
        float a = ws[OFF_BASE];
        #pragma unroll
        for (int j = 0; j < 3; j++) {
            int wg = w0 + tid + j - 1;
            a += zlds[j*84 + tid + j];
            if (wg >= 0 && wg < Wd) a += ws[OFF_H + j];
        }
        ws[OFF_XSEQ + (size_t)b*Wd + w0 + tid] = a;
    }

    // ---- Gram via MFMA: wave wv owns q-tile wv (rows wv*16..) and k-tile wv
    // (rows 64+wv*16..) — both written by THIS wave above (nt=wv, nt=wv+4).
    {
        const int rq = (wv*16 + lr) * 144;
        const int rk = (64 + wv*16 + lr) * 144;
        const int ko = g * 16;     // byte offset of this lane's k-group
        f32x4 sqk = (f32x4){0,0,0,0}, sqq = (f32x4){0,0,0,0}, skk = (f32x4){0,0,0,0};
        #pragma unroll
        for (int kb = 0; kb < 2; kb++) {
            int off = kb*64 + ko;
            bf16x8 qh = *(const bf16x8*)((unsigned char*)qkhi + rq + off);
            bf16x8 ql = *(const bf16x8*)((unsigned char*)qklo + rq + off);
            bf16x8 kh = *(const bf16x8*)((unsigned char*)qkhi + rk + off);
            bf16x8 kl = *(const bf16x8*)((unsigned char*)qklo + rk + off);
            sqk = __builtin_amdgcn_mfma_f32_16x16x32_bf16(qh, kh, sqk, 0,0,0);
            sqk = __builtin_amdgcn_mfma_f32_16x16x32_bf16(ql, kh, sqk, 0,0,0);
            sqk = __builtin_amdgcn_mfma_f32_16x16x32_bf16(qh, kl, sqk, 0,0,0);
            sqq = __builtin_amdgcn_mfma_f32_16x16x32_bf16(qh, qh, sqq, 0,0,0);
            sqq = __builtin_amdgcn_mfma_f32_16x16x32_bf16(ql, qh, sqq, 0,0,0);
            sqq = __builtin_amdgcn_mfma_f32_16x16x32_bf16(qh, ql, sqq, 0,0,0);
            skk = __builtin_amdgcn_mfma_f32_16x16x32_bf16(kh, kh, skk, 0,0,0);
            skk = __builtin_amdgcn_mfma_f32_16x16x32_bf16(kl, kh, skk, 0,0,0);
            skk = __builtin_amdgcn_mfma_f32_16x16x32_bf16(kh, kl, skk, 0,0,0);
        }
        float* pb = ws + OFF_PART + (size_t)b*640*128 + tile;   // + idx*128
        int hh = lr >> 3, c2 = lr & 7;
        if (hh == (g >> 1)) {
            #pragma unroll
            for (int r = 0; r < 4; r++) {
                int c1 = (g & 1)*4 + r;
                int idx = (2*wv + hh)*64 + c1*8 + c2;
                pb[(size_t)idx*128] = sqk[r];
            }
        }
        if ((lr >> 2) == g) {
            int r = lr & 3;
            pb[(size_t)(512 + wv*16 + lr)*128] = sqq[r];
            pb[(size_t)(576 + wv*16 + lr)*128] = skk[r];
        }
    }
}

// ---------------- k23: role A (bx<32): reduce part -> S ; role B: MTL scalars
__device__ __forceinline__ float blk_reduce_256(float v, float* sc) {
    #pragma unroll
    for (int off = 32; off > 0; off >>= 1) v += __shfl_down(v, off, 64);
    __syncthreads();
    if ((threadIdx.x & 63) == 0) sc[threadIdx.x >> 6] = v;
    __syncthreads();
    return sc[0] + sc[1] + sc[2] + sc[3];
}

__global__ __launch_bounds__(256) void k23(const float* __restrict__ ws,
    const float* __restrict__ up_w, const float* __restrict__ up_b,
    const float* __restrict__ c2_w, const float* __restrict__ c2_b,
    const float* __restrict__ ln2_w, const float* __restrict__ ln2_b,
    const float* __restrict__ c4_w, const float* __restrict__ c4_b,
    const float* __restrict__ ln4_w, const float* __restrict__ ln4_b,
    const float* __restrict__ c6_w, const float* __restrict__ c6_b,
    const float* __restrict__ ln6_w, const float* __restrict__ ln6_b,
    float* __restrict__ wsS, float* __restrict__ wsM)
{
    __shared__ float ys[Wd];
    __shared__ float sc[4];
    int bx = blockIdx.x;
    if (bx < 32) {
        // ---- k2 role: S[b][idx] = sum over 128 tiles (coalesced f4 chains)
        int b = bx;
        const float* part = ws + OFF_PART;
        for (int idx = threadIdx.x; idx < 640; idx += 256) {
            const float4* p = (const float4*)(part + ((size_t)b*640 + idx)*128);
            float s = 0.f;
            #pragma unroll 8
            for (int i = 0; i < 32; i++) {
                float4 t = p[i];
                s += ((t.x + t.y) + (t.z + t.w));
            }
            wsS[b*640 + idx] = s;
        }
        return;
    }
    // ---- k3 role: branch br of batch b
    int t2 = bx - 32;
    int br = t2 / 32, b = t2 % 32;
    const float *cw, *lw, *lb; float cb; int K, lo;
    if (br == 0)      { cw = c2_w; cb = c2_b[0]; lw = ln2_w; lb = ln2_b; K = 2; lo = 0; }
    else if (br == 1) { cw = c4_w; cb = c4_b[0]; lw = ln4_w; lb = ln4_b; K = 4; lo = 1; }
    else              { cw = c6_w; cb = c6_b[0]; lw = ln6_w; lb = ln6_b; K = 6; lo = 2; }
    float uw = up_w[br], ub = up_b[br];
    const float* xr = ws + OFF_XSEQ + (size_t)b*Wd;

    float s = 0.f, s2 = 0.f;
    for (int w = threadIdx.x; w < Wd; w += 256) {
        float y = cb;
        for (int m = 0; m < K; m++) {
            int p = w + m - lo;
            if (p >= 0 && p < Wd) y += cw[m] * (uw*xr[p] + ub);
        }
        ys[w] = y; s += y; s2 += y*y;
    }
    float mu = blk_reduce_256(s, sc) * (1.f/Wd);
    __syncthreads();
    float Ey2 = blk_reduce_256(s2, sc) * (1.f/Wd);
    float var = fmaxf(Ey2 - mu*mu, 0.f);
    float inv = 1.f / sqrtf(var + 1e-5f);
    float se = 0.f;
    for (int w = threadIdx.x; w < Wd; w += 256) {
        float tt = (ys[w]-mu)*inv*lw[w] + lb[w];
        se += (tt > 0.f) ? tt : expm1f(tt);
    }
    float m = blk_reduce_256(se, sc) * (1.f/Wd);
    if (threadIdx.x == 0) wsM[b*3 + br] = m;
}

// ---------------- k45: per-b coeffs (E,F) + streamed output write
__global__ __launch_bounds__(256) void k45(const float* __restrict__ ws,
    const float* __restrict__ temperature,
    const float* __restrict__ mp_w, const float* __restrict__ mp_b,
    const float* __restrict__ up_w, const float* __restrict__ up_b,
    const float* __restrict__ proj_w, const float* __restrict__ proj_b,
    float* __restrict__ out)
{
    __shared__ float snk[64], sal[64], sbe[64], sE[64], sF[64];
    const int tid = threadIdx.x;
    const int chunk = blockIdx.x, b = blockIdx.y;
    const float* Sb = ws + OFF_S + b*640;
    float nq = 0.f;
    if (tid < 64) {
        nq = fmaxf(sqrtf(Sb[512 + tid]), 1e-12f);
        snk[tid] = fmaxf(sqrtf(Sb[576 + tid]), 1e-12f);
    }
    __syncthreads();
    if (tid < 64) {
        int h = tid >> 3;
        float temp = temperature[h];
        float lg[8], mx = -1e30f;
        #pragma unroll
        for (int d = 0; d < 8; d++) {
            lg[d] = Sb[8*tid + d] / (nq * snk[h*8 + d]) * temp;
            mx = fmaxf(mx, lg[d]);
        }
        float sum = 0.f;
        #pragma unroll
        for (int d = 0; d < 8; d++) { lg[d] = expf(lg[d] - mx); sum += lg[d]; }
        float a = 0.f, bb = 0.f;
        #pragma unroll
        for (int d = 0; d < 8; d++) {
            float at = lg[d] / sum;
            a  += at * mp_w[h*8 + d];
            bb += at * mp_b[h*8 + d];
        }
        sal[tid] = a; sbe[tid] = bb;
    }
    __syncthreads();
    if (tid < 64) {
        const float* wm = ws + OFF_M + b*3;
        float m2 = wm[0], m4 = wm[1], m6 = wm[2];
        float A = m2*up_w[0] + m4*up_w[1] + m6*up_w[2];
        float C = m2*up_b[0] + m4*up_b[1] + m6*up_b[2];
        float Pa = 0.f, Pb = 0.f;
        for (int c = 0; c < 64; c++) {
            float pw = proj_w[tid*64 + c];
            Pa += pw * sal[c];
            Pb += pw * sbe[c];
        }
        sE[tid] = A * Pa;
        sF[tid] = C * Pa + Pb + proj_b[tid];
    }
    __syncthreads();
    // write: out[b][o][chunk*512 .. +512) = E*xseq + F
    const float4* xs4 = (const float4*)(ws + OFF_XSEQ + (size_t)b*Wd);
    float4 xv = xs4[chunk*128 + (tid & 127)];
    int ohalf = tid >> 7;
    float4* ob = (float4*)out + (size_t)b*64*2048 + chunk*128 + (tid & 127);
    #pragma unroll 8
    for (int oo = 0; oo < 32; oo++) {
        int o = ohalf*32 + oo;
        float e = sE[o], f = sF[o];
        float4 r = { e*xv.x + f, e*xv.y + f, e*xv.z + f, e*xv.w + f };
        ob[(size_t)o*2048] = r;
    }
}

extern "C" void kernel_launch(void* const* d_in, const int* in_sizes, int n_in,
                              void* d_out, int out_size, void* d_ws, size_t ws_size,
                              hipStream_t stream) {
    const float* x      = (const float*)d_in[0];
    const float* qkv_w  = (const float*)d_in[1];
    const float* qkv_b  = (const float*)d_in[2];
    const float* dw_w   = (const float*)d_in[3];
    const float* dw_b   = (const float*)d_in[4];
    const float* proj_w = (const float*)d_in[5];
    const float* proj_b = (const float*)d_in[6];
    const float* temperature = (const float*)d_in[7];
    const float* sp_w   = (const float*)d_in[8];
    const float* sp_b   = (const float*)d_in[9];
    const float* up_w   = (const float*)d_in[10];
    const float* up_b   = (const float*)d_in[11];
    const float* c2_w   = (const float*)d_in[12];
    const float* c2_b   = (const float*)d_in[13];
    const float* ln2_w  = (const float*)d_in[14];
    const float* ln2_b  = (const float*)d_in[15];
    const float* c4_w   = (const float*)d_in[16];
    const float* c4_b   = (const float*)d_in[17];
    const float* ln4_w  = (const float*)d_in[18];
    const float* ln4_b  = (const float*)d_in[19];
    const float* c6_w   = (const float*)d_in[20];
    const float* c6_b   = (const float*)d_in[21];
    const float* ln6_w  = (const float*)d_in[22];
    const float* ln6_b  = (const float*)d_in[23];
    const float* mp_w   = (const float*)d_in[24];
    const float* mp_b   = (const float*)d_in[25];
    float* ws  = (float*)d_ws;
    float* out = (float*)d_out;

    k0_setup<<<1, 256, 0, stream>>>(qkv_w, qkv_b, dw_w, dw_b, sp_w, sp_b, ws);
    k1_main<<<dim3(128, 32), 256, 0, stream>>>(x, qkv_b, dw_w, dw_b, ws);
    k23<<<128, 256, 0, stream>>>(ws, up_w, up_b,
        c2_w, c2_b, ln2_w, ln2_b, c4_w, c4_b, ln4_w, ln4_b, c6_w, c6_b, ln6_w, ln6_b,
        ws + OFF_S, ws + OFF_M);
    k45<<<dim3(16, 32), 256, 0, stream>>>(ws, temperature, mp_w, mp_b,
        up_w, up_b, proj_w, proj_b, out);
}

// Round 4
// 126.244 us; speedup vs baseline: 2.4923x; 1.1460x over previous
//
#include <hip/hip_runtime.h>
#include <hip/hip_bf16.h>
#include <math.h>

#define Wd 8192
#define Bd 32
#define Ttile 64

// ws layout (float offsets)
#define OFF_G    0                          // 3*64
#define OFF_H    192                        // 3
#define OFF_BASE 195                        // 1
#define OFF_XSEQ 256                        // 32*8192
#define OFF_PART (256 + Bd*Wd)              // [b][128 tiles][640] contiguous per block
#define OFF_S    (OFF_PART + Bd*128*640)    // 32*640
#define OFF_M    (OFF_S + Bd*640)           // 32*3
#define OFF_E    (OFF_M + 96)
#define OFF_F    (OFF_E + Bd*64)
#define OFF_FRAG (OFF_F + Bd*64)            // 2 ver * 9 nt * 2 kb * 64 lane * uint4

typedef __attribute__((ext_vector_type(8))) short bf16x8;
typedef __attribute__((ext_vector_type(4))) float f32x4;

__device__ __forceinline__ unsigned short f2bf(float v) {
    return __builtin_bit_cast(unsigned short, __float2bfloat16(v));
}
__device__ __forceinline__ float bf2f(unsigned short h) {
    return __builtin_bit_cast(float, (unsigned)h << 16);
}
__device__ __forceinline__ void split2(float v0, float v1, unsigned& hw, unsigned& lw) {
    unsigned short h0 = f2bf(v0), h1 = f2bf(v1);
    unsigned short l0 = f2bf(v0 - bf2f(h0)), l1 = f2bf(v1 - bf2f(h1));
    hw = (unsigned)h0 | ((unsigned)h1 << 16);
    lw = (unsigned)l0 | ((unsigned)l1 << 16);
}
__device__ __forceinline__ unsigned pk2(float v0, float v1) {
    return (unsigned)f2bf(v0) | ((unsigned)f2bf(v1) << 16);
}

// ---------------- k0: fold sp_w through dwconv(V)+qkv into g/h/base; pack
// hi/lo bf16 B-fragments (col = weight-row, k = channel) of the 131x64 matrix.
__global__ __launch_bounds__(256) void k0_setup(const float* __restrict__ qkv_w,
                         const float* __restrict__ qkv_b,
                         const float* __restrict__ dw_w, const float* __restrict__ dw_b,
                         const float* __restrict__ sp_w, const float* __restrict__ sp_b,
                         float* __restrict__ ws)
{
    int tid = threadIdx.x;
    if (tid < 192) {
        int j = tid >> 6, ch = tid & 63;
        float acc = 0.f;
        for (int c = 0; c < 64; c++)
            acc += sp_w[c] * dw_w[(128+c)*9 + 3 + j] * qkv_w[(128+c)*64 + ch];
        ws[OFF_G + j*64 + ch] = acc;
    } else if (tid < 195) {
        int j = tid - 192;
        float h = 0.f;
        for (int c = 0; c < 64; c++)
            h += sp_w[c] * dw_w[(128+c)*9 + 3 + j] * qkv_b[128+c];
        ws[OFF_H + j] = h;
    } else if (tid == 195) {
        float base = sp_b[0];
        for (int c = 0; c < 64; c++) base += sp_w[c] * dw_b[128+c];
        ws[OFF_BASE] = base;
    }
    __syncthreads();
    for (int it = tid; it < 36*64; it += 256) {
        int lane = it & 63;
        int cidx = it >> 6;          // 0..35
        int ver = cidx / 18;
        int rem = cidx - ver*18;
        int nt = rem >> 1, kb = rem & 1;
        int row = nt*16 + (lane & 15);
        int ks  = kb*32 + (lane >> 4)*8;
        unsigned short u[8];
        #pragma unroll
        for (int e = 0; e < 8; e++) {
            int k = ks + e;
            float v = 0.f;
            if (row < 128)      v = qkv_w[row*64 + k];
            else if (row < 131) v = ws[OFF_G + (row-128)*64 + k];
            unsigned short h = f2bf(v);
            if (ver == 0) u[e] = h;
            else          u[e] = f2bf(v - bf2f(h));
        }
        unsigned* dst = (unsigned*)(ws + OFF_FRAG) + (ver*1152 + (nt*2+kb)*64 + lane)*4;
        dst[0] = (unsigned)u[0] | ((unsigned)u[1] << 16);
        dst[1] = (unsigned)u[2] | ((unsigned)u[3] << 16);
        dst[2] = (unsigned)u[4] | ((unsigned)u[5] << 16);
        dst[3] = (unsigned)u[6] | ((unsigned)u[7] << 16);
    }
}

// ---------------- k1: staged-LDS MFMA projection + reg-conv + MFMA Gram
// LDS layout (bytes):
//   xt_hi [84 rows][128B]  (row = pos-(w0-4); 32 u32 ch-pairs, 16B-granule XOR swz)
//   xt_lo same
//   qkh   [128 rows][128B] (row = W-row, cols = slots as bf16, granule XOR swz)
//   zlds  3*84 f32
#define XT_HI 0
#define XT_LO 10752
#define QKH   21504
#define ZLDS  37888
#define SMEM_BYTES (37888 + 1024)

__global__ __launch_bounds__(256, 4) void k1_main(const float* __restrict__ x,
    const float* __restrict__ qkv_b, const float* __restrict__ dw_w,
    const float* __restrict__ dw_b, float* __restrict__ ws)
{
    __shared__ __align__(16) unsigned char smem[SMEM_BYTES];
    const int tid = threadIdx.x, lane = tid & 63, wv = tid >> 6;
    const int g = lane >> 4, lr = lane & 15;
    const int tile = blockIdx.x, b = blockIdx.y;
    const int w0 = tile * Ttile;
    const float* xb = x + (size_t)b * 64 * Wd;
    const bool safe = (tile != 0) && (tile != 127);

    // ---- staging: coalesced f4 loads, split hi/lo, transposed swizzled LDS
    // item i: j = i/32 (0..20, 4 rows each), chp = i%32 (channel pair)
    for (int i = tid; i < 672; i += 256) {
        int j = i >> 5, chp = i & 31;
        int pos0 = w0 - 4 + 4*j;
        float4 a, c;
        if (safe || (unsigned)pos0 < (unsigned)Wd) {
            a = *(const float4*)(xb + (size_t)(2*chp)*Wd + pos0);
            c = *(const float4*)(xb + (size_t)(2*chp+1)*Wd + pos0);
        } else {
            a = (float4){0,0,0,0}; c = (float4){0,0,0,0};
        }
        #pragma unroll
        for (int e = 0; e < 4; e++) {
            int row = 4*j + e;
            float va = ((const float*)&a)[e], vc = ((const float*)&c)[e];
            unsigned hw, lw;
            split2(va, vc, hw, lw);
            int boff = row*128 + ((((chp>>2) ^ (row & 7)) << 4) | ((chp & 3) << 2));
            *(unsigned*)(smem + XT_HI + boff) = hw;
            *(unsigned*)(smem + XT_LO + boff) = lw;
        }
    }
    __syncthreads();

    // ---- GEMM: C(80 slots x 131 W-rows) = X^T @ W^T, hi/lo 3-pass
    // slot s (0..79) <-> pos = w0-1+s <-> xt row = s+3
    f32x4 acc[3][5];
    #pragma unroll
    for (int i = 0; i < 3; i++)
        #pragma unroll
        for (int m = 0; m < 5; m++) acc[i][m] = (f32x4){0.f,0.f,0.f,0.f};
    const uint4* fragbase = (const uint4*)(ws + OFF_FRAG);

    #pragma unroll
    for (int kb = 0; kb < 2; kb++) {
        bf16x8 axh[5], axl[5];
        #pragma unroll
        for (int mt = 0; mt < 5; mt++) {
            int row = mt*16 + lr + 3;
            int gran = (kb*4 + g) ^ (row & 7);
            axh[mt] = *(const bf16x8*)(smem + XT_HI + row*128 + gran*16);
            axl[mt] = *(const bf16x8*)(smem + XT_LO + row*128 + gran*16);
        }
        #pragma unroll
        for (int nti = 0; nti < 3; nti++) {
            if (nti < 2 || wv == 0) {
                int nt = (nti == 2) ? 8 : (wv + nti*4);
                bf16x8 bh = __builtin_bit_cast(bf16x8, fragbase[(nt*2+kb)*64 + lane]);
                bf16x8 bl = __builtin_bit_cast(bf16x8, fragbase[1152 + (nt*2+kb)*64 + lane]);
                #pragma unroll
                for (int mt = 0; mt < 5; mt++) {
                    acc[nti][mt] = __builtin_amdgcn_mfma_f32_16x16x32_bf16(axh[mt], bh, acc[nti][mt], 0,0,0);
                    acc[nti][mt] = __builtin_amdgcn_mfma_f32_16x16x32_bf16(axl[mt], bh, acc[nti][mt], 0,0,0);
                    acc[nti][mt] = __builtin_amdgcn_mfma_f32_16x16x32_bf16(axh[mt], bl, acc[nti][mt], 0,0,0);
                }
            }
        }
    }

    // ---- epilogue: lane holds W-row nt*16+lr, slots mt*16+g*4+r
    float* zlds = (float*)(smem + ZLDS);
    #pragma unroll
    for (int nti = 0; nti < 3; nti++) {
        if (!(nti < 2 || wv == 0)) continue;
        int nt = (nti == 2) ? 8 : (wv + nti*4);
        int row = nt*16 + lr;
        if (nt == 8) {
            if (lr < 3) {
                #pragma unroll
                for (int mt = 0; mt < 5; mt++) {
                    float4 vz = { acc[2][mt][0], acc[2][mt][1], acc[2][mt][2], acc[2][mt][3] };
                    *(float4*)(zlds + lr*84 + mt*16 + g*4) = vz;
                }
            }
        } else {
            float bias = qkv_b[row];
            float tb = dw_b[row];
            float t0 = dw_w[row*9+3], t1 = dw_w[row*9+4], t2 = dw_w[row*9+5];
            float4 v[5];
            #pragma unroll
            for (int mt = 0; mt < 5; mt++) {
                #pragma unroll
                for (int r = 0; r < 4; r++) {
                    float val = acc[nti][mt][r] + bias;
                    if (!safe) {
                        int pos = w0 - 1 + mt*16 + g*4 + r;
                        if (pos < 0 || pos >= Wd) val = 0.f;
                    }
                    ((float*)&v[mt])[r] = val;
                }
            }
            int src = (lane + 16) & 63;
            #pragma unroll
            for (int mt = 0; mt < 4; mt++) {
                float a0 = __shfl(v[mt].x,   src), b0 = __shfl(v[mt+1].x, src);
                float a1 = __shfl(v[mt].y,   src), b1 = __shfl(v[mt+1].y, src);
                float in4 = (lane < 48) ? a0 : b0;
                float in5 = (lane < 48) ? a1 : b1;
                float o0 = tb + t0*v[mt].x + t1*v[mt].y + t2*v[mt].z;
                float o1 = tb + t0*v[mt].y + t1*v[mt].z + t2*v[mt].w;
                float o2 = tb + t0*v[mt].z + t1*v[mt].w + t2*in4;
                float o3 = tb + t0*v[mt].w + t1*in4     + t2*in5;
                uint2 hw;
                hw.x = pk2(o0, o1);
                hw.y = pk2(o2, o3);
                int gran = (2*mt + (g>>1)) ^ (row & 7);
                int boff = row*128 + (gran << 4) + ((g & 1) << 3);
                *(uint2*)(smem + QKH + boff) = hw;
            }
        }
    }

    // ---- xseq (wave 0 only; zlds written by wave 0)
    if (tid < 64) {
        float a = ws[OFF_BASE];
        #pragma unroll
        for (int j = 0; j < 3; j++) {
            int wg = w0 + tid + j - 1;
            a += zlds[j*84 + tid + j];
            if (wg >= 0 && wg < Wd) a += ws[OFF_H + j];
        }
        ws[OFF_XSEQ + (size_t)b*Wd + w0 + tid] = a;
    }

    // ---- Gram via MFMA (bf16-hi only): wave wv owns q rows wv*16.., k rows 64+wv*16..
    {
        const int rq = wv*16 + lr;
        const int rk = 64 + wv*16 + lr;
        f32x4 sqk = (f32x4){0,0,0,0}, sqq = (f32x4){0,0,0,0}, skk = (f32x4){0,0,0,0};
        #pragma unroll
        for (int kb = 0; kb < 2; kb++) {
            int gran = (kb*4 + g) ^ (lr & 7);
            bf16x8 qh = *(const bf16x8*)(smem + QKH + rq*128 + gran*16);
            bf16x8 kh = *(const bf16x8*)(smem + QKH + rk*128 + gran*16);
            sqk = __builtin_amdgcn_mfma_f32_16x16x32_bf16(qh, kh, sqk, 0,0,0);
            sqq = __builtin_amdgcn_mfma_f32_16x16x32_bf16(qh, qh, sqq, 0,0,0);
            skk = __builtin_amdgcn_mfma_f32_16x16x32_bf16(kh, kh, skk, 0,0,0);
        }
        float* pb = ws + OFF_PART + (size_t)(b*128 + tile)*640;
        int hh = lr >> 3, c2 = lr & 7;
        if (hh == (g >> 1)) {
            #pragma unroll
            for (int r = 0; r < 4; r++) {
                int c1 = (g & 1)*4 + r;
                pb[(2*wv + hh)*64 + c1*8 + c2] = sqk[r];
            }
        }
        if ((lr >> 2) == g) {
            int r = lr & 3;
            pb[512 + wv*16 + lr] = sqq[r];
            pb[576 + wv*16 + lr] = skk[r];
        }
    }
}

// ---------------- k23: role A (bx<32): reduce part -> S ; role B: MTL scalars
__device__ __forceinline__ float blk_reduce_256(float v, float* sc) {
    #pragma unroll
    for (int off = 32; off > 0; off >>= 1) v += __shfl_down(v, off, 64);
    __syncthreads();
    if ((threadIdx.x & 63) == 0) sc[threadIdx.x >> 6] = v;
    __syncthreads();
    return sc[0] + sc[1] + sc[2] + sc[3];
}

__global__ __launch_bounds__(256) void k23(const float* __restrict__ ws,
    const float* __restrict__ up_w, const float* __restrict__ up_b,
    const float* __restrict__ c2_w, const float* __restrict__ c2_b,
    const float* __restrict__ ln2_w, const float* __restrict__ ln2_b,
    const float* __restrict__ c4_w, const float* __restrict__ c4_b,
    const float* __restrict__ ln4_w, const float* __restrict__ ln4_b,
    const float* __restrict__ c6_w, const float* __restrict__ c6_b,
    const float* __restrict__ ln6_w, const float* __restrict__ ln6_b,
    float* __restrict__ wsS, float* __restrict__ wsM)
{
    __shared__ float ys[Wd];
    __shared__ float sc[4];
    int bx = blockIdx.x;
    if (bx < 32) {
        // S[b][idx] = sum over 128 tiles; coalesced across threads
        int b = bx;
        const float* part = ws + OFF_PART + (size_t)b*128*640;
        #pragma unroll
        for (int k = 0; k < 3; k++) {
            int idx = threadIdx.x + k*256;
            if (idx < 640) {
                float s0 = 0.f, s1 = 0.f, s2 = 0.f, s3 = 0.f;
                for (int t = 0; t < 128; t += 4) {
                    s0 += part[(size_t)(t  )*640 + idx];
                    s1 += part[(size_t)(t+1)*640 + idx];
                    s2 += part[(size_t)(t+2)*640 + idx];
                    s3 += part[(size_t)(t+3)*640 + idx];
                }
                wsS[b*640 + idx] = (s0 + s1) + (s2 + s3);
            }
        }
        return;
    }
    int t2 = bx - 32;
    int br = t2 / 32, b = t2 % 32;
    const float *cw, *lw, *lb; float cb; int K, lo;
    if (br == 0)      { cw = c2_w; cb = c2_b[0]; lw = ln2_w; lb = ln2_b; K = 2; lo = 0; }
    else if (br == 1) { cw = c4_w; cb = c4_b[0]; lw = ln4_w; lb = ln4_b; K = 4; lo = 1; }
    else              { cw = c6_w; cb = c6_b[0]; lw = ln6_w; lb = ln6_b; K = 6; lo = 2; }
    float uw = up_w[br], ub = up_b[br];
    const float* xr = ws + OFF_XSEQ + (size_t)b*Wd;

    float s = 0.f, s2 = 0.f;
    for (int w = threadIdx.x; w < Wd; w += 256) {
        float y = cb;
        for (int m = 0; m < K; m++) {
            int p = w + m - lo;
            if (p >= 0 && p < Wd) y += cw[m] * (uw*xr[p] + ub);
        }
        ys[w] = y; s += y; s2 += y*y;
    }
    float mu = blk_reduce_256(s, sc) * (1.f/Wd);
    __syncthreads();
    float Ey2 = blk_reduce_256(s2, sc) * (1.f/Wd);
    float var = fmaxf(Ey2 - mu*mu, 0.f);
    float inv = 1.f / sqrtf(var + 1e-5f);
    float se = 0.f;
    for (int w = threadIdx.x; w < Wd; w += 256) {
        float tt = (ys[w]-mu)*inv*lw[w] + lb[w];
        se += (tt > 0.f) ? tt : expm1f(tt);
    }
    float m = blk_reduce_256(se, sc) * (1.f/Wd);
    if (threadIdx.x == 0) wsM[b*3 + br] = m;
}

// ---------------- k45: per-b coeffs (E,F) + streamed output write
__global__ __launch_bounds__(256) void k45(const float* __restrict__ ws,
    const float* __restrict__ temperature,
    const float* __restrict__ mp_w, const float* __restrict__ mp_b,
    const float* __restrict__ up_w, const float* __restrict__ up_b,
    const float* __restrict__ proj_w, const float* __restrict__ proj_b,
    float* __restrict__ out)
{
    __shared__ float snk[64], sal[64], sbe[64], sE[64], sF[64];
    const int tid = threadIdx.x;
    const int chunk = blockIdx.x, b = blockIdx.y;
    const float* Sb = ws + OFF_S + b*640;
    float nq = 0.f;
    if (tid < 64) {
        nq = fmaxf(sqrtf(Sb[512 + tid]), 1e-12f);
        snk[tid] = fmaxf(sqrtf(Sb[576 + tid]), 1e-12f);
    }
    __syncthreads();
    if (tid < 64) {
        int h = tid >> 3;
        float temp = temperature[h];
        float lg[8], mx = -1e30f;
        #pragma unroll
        for (int d = 0; d < 8; d++) {
            lg[d] = Sb[8*tid + d] / (nq * snk[h*8 + d]) * temp;
            mx = fmaxf(mx, lg[d]);
        }
        float sum = 0.f;
        #pragma unroll
        for (int d = 0; d < 8; d++) { lg[d] = expf(lg[d] - mx); sum += lg[d]; }
        float a = 0.f, bb = 0.f;
        #pragma unroll
        for (int d = 0; d < 8; d++) {
            float at = lg[d] / sum;
            a  += at * mp_w[h*8 + d];
            bb += at * mp_b[h*8 + d];
        }
        sal[tid] = a; sbe[tid] = bb;
    }
    __syncthreads();
    if (tid < 64) {
        const float* wm = ws + OFF_M + b*3;
        float m2 = wm[0], m4 = wm[1], m6 = wm[2];
        float A = m2*up_w[0] + m4*up_w[1] + m6*up_w[2];
        float C = m2*up_b[0] + m4*up_b[1] + m6*up_b[2];
        float Pa = 0.f, Pb = 0.f;
        for (int c = 0; c < 64; c++) {
            float pw = proj_w[tid*64 + c];
            Pa += pw * sal[c];
            Pb += pw * sbe[c];
        }
        sE[tid] = A * Pa;
        sF[tid] = C * Pa + Pb + proj_b[tid];
    }
    __syncthreads();
    const float4* xs4 = (const float4*)(ws + OFF_XSEQ + (size_t)b*Wd);
    float4 xv = xs4[chunk*128 + (tid & 127)];
    int ohalf = tid >> 7;
    float4* ob = (float4*)out + (size_t)b*64*2048 + chunk*128 + (tid & 127);
    #pragma unroll 8
    for (int oo = 0; oo < 32; oo++) {
        int o = ohalf*32 + oo;
        float e = sE[o], f = sF[o];
        float4 r = { e*xv.x + f, e*xv.y + f, e*xv.z + f, e*xv.w + f };
        ob[(size_t)o*2048] = r;
    }
}

extern "C" void kernel_launch(void* const* d_in, const int* in_sizes, int n_in,
                              void* d_out, int out_size, void* d_ws, size_t ws_size,
                              hipStream_t stream) {
    const float* x      = (const float*)d_in[0];
    const float* qkv_w  = (const float*)d_in[1];
    const float* qkv_b  = (const float*)d_in[2];
    const float* dw_w   = (const float*)d_in[3];
    const float* dw_b   = (const float*)d_in[4];
    const float* proj_w = (const float*)d_in[5];
    const float* proj_b = (const float*)d_in[6];
    const float* temperature = (const float*)d_in[7];
    const float* sp_w   = (const float*)d_in[8];
    const float* sp_b   = (const float*)d_in[9];
    const float* up_w   = (const float*)d_in[10];
    const float* up_b   = (const float*)d_in[11];
    const float* c2_w   = (const float*)d_in[12];
    const float* c2_b   = (const float*)d_in[13];
    const float* ln2_w  = (const float*)d_in[14];
    const float* ln2_b  = (const float*)d_in[15];
    const float* c4_w   = (const float*)d_in[16];
    const float* c4_b   = (const float*)d_in[17];
    const float* ln4_w  = (const float*)d_in[18];
    const float* ln4_b  = (const float*)d_in[19];
    const float* c6_w   = (const float*)d_in[20];
    const float* c6_b   = (const float*)d_in[21];
    const float* ln6_w  = (const float*)d_in[22];
    const float* ln6_b  = (const float*)d_in[23];
    const float* mp_w   = (const float*)d_in[24];
    const float* mp_b   = (const float*)d_in[25];
    float* ws  = (float*)d_ws;
    float* out = (float*)d_out;

    k0_setup<<<1, 256, 0, stream>>>(qkv_w, qkv_b, dw_w, dw_b, sp_w, sp_b, ws);
    k1_main<<<dim3(128, 32), 256, 0, stream>>>(x, qkv_b, dw_w, dw_b, ws);
    k23<<<128, 256, 0, stream>>>(ws, up_w, up_b,
        c2_w, c2_b, ln2_w, ln2_b, c4_w, c4_b, ln4_w, ln4_b, c6_w, c6_b, ln6_w, ln6_b,
        ws + OFF_S, ws + OFF_M);
    k45<<<dim3(16, 32), 256, 0, stream>>>(ws, temperature, mp_w, mp_b,
        up_w, up_b, proj_w, proj_b, out);
}